// Round 1
// baseline (213.287 us; speedup 1.0000x reference)
//
#include <hip/hip_runtime.h>

// YOLO loss: BATCH=16384, SNUM=7 -> CELLS=49, BNUM=2, CLSS=20 -> ELE=30.
// Memory-bound streaming reduction: 193 MB in, 4 B out.

#define ELE 30
#define PAD 31          // +1 pad: LDS stride 31 == -1 mod 32 -> conflict-free
#define CPB 256         // cells per block (== threads per block)
#define TPB 256
#define TOTAL_CELLS (16384 * 49)   // 802816; /256 = 3136 blocks exactly

__global__ __launch_bounds__(TPB) void yolo_loss_kernel(
    const float* __restrict__ P, const float* __restrict__ T,
    float* __restrict__ out)
{
    __shared__ float sP[CPB * PAD];
    __shared__ float sT[CPB * PAD];
    __shared__ float swave[TPB / 64];

    const int tid = threadIdx.x;
    const size_t base = (size_t)blockIdx.x * (CPB * ELE);   // floats; *4B = 30720 -> 16B aligned
    const float4* P4 = reinterpret_cast<const float4*>(P + base);
    const float4* T4 = reinterpret_cast<const float4*>(T + base);
    const int NV = CPB * ELE / 4;   // 1920 float4s per input

    // Coalesced float4 staging: 16 B/lane, scatter into padded LDS layout.
    for (int v = tid; v < NV; v += TPB) {
        float4 pv = P4[v];
        float4 tv = T4[v];
        const float* pf = &pv.x;
        const float* tf = &tv.x;
        int e = v * 4;
        #pragma unroll
        for (int j = 0; j < 4; ++j) {
            int ee = e + j;
            int cell = ee / ELE;            // magic-mul div by 30
            int off  = ee - cell * ELE;
            int idx  = cell * PAD + off;
            sP[idx] = pf[j];
            sT[idx] = tf[j];
        }
    }
    __syncthreads();

    // ---- per-cell loss ----
    const float* cp = &sP[tid * PAD];
    const float* ct = &sT[tid * PAD];

    const float conf_flag = ct[5];
    const float coord = (conf_flag > 0.0f) ? 1.0f : 0.0f;
    const float noobj = (conf_flag == 0.0f) ? 1.0f : 0.0f;

    // confidence diffs (fields 4 and 9)
    const float dc0 = cp[4] - ct[4];
    const float dc1 = cp[9] - ct[9];
    const float noobj_conf = noobj * (dc0 * dc0 + dc1 * dc1);

    // corners + areas (areas from corners, matching reference rounding)
    float px1[2], py1[2], px2[2], py2[2], pa[2];
    float tx1[2], ty1[2], tx2[2], ty2[2], ta[2];
    #pragma unroll
    for (int b = 0; b < 2; ++b) {
        const int o = b * 5;
        float cx = cp[o + 0], cy = cp[o + 1], w = cp[o + 2], h = cp[o + 3];
        px1[b] = cx - w * 0.5f; py1[b] = cy - h * 0.5f;
        px2[b] = cx + w * 0.5f; py2[b] = cy + h * 0.5f;
        pa[b]  = (px2[b] - px1[b]) * (py2[b] - py1[b]);
        cx = ct[o + 0]; cy = ct[o + 1]; w = ct[o + 2]; h = ct[o + 3];
        tx1[b] = cx - w * 0.5f; ty1[b] = cy - h * 0.5f;
        tx2[b] = cx + w * 0.5f; ty2[b] = cy + h * 0.5f;
        ta[b]  = (tx2[b] - tx1[b]) * (ty2[b] - ty1[b]);
    }

    // pairwise IoU: iou[p][t]
    float iou[2][2];
    #pragma unroll
    for (int p = 0; p < 2; ++p) {
        #pragma unroll
        for (int t = 0; t < 2; ++t) {
            float lx = fmaxf(px1[p], tx1[t]);
            float ly = fmaxf(py1[p], ty1[t]);
            float rx = fminf(px2[p], tx2[t]);
            float ry = fminf(py2[p], ty2[t]);
            float iw = fmaxf(rx - lx, 0.0f);
            float ih = fmaxf(ry - ly, 0.0f);
            float inter = iw * ih;
            iou[p][t] = inter / (pa[p] + ta[t] - inter + 1e-10f);
        }
    }

    // argmax over p per target t; first-max tiebreak -> strict '>' for idx 1
    const int b0 = (iou[1][0] > iou[0][0]) ? 1 : 0;
    const int b1 = (iou[1][1] > iou[0][1]) ? 1 : 0;
    const float resp0 = coord * ((b0 == 0 || b1 == 0) ? 1.0f : 0.0f);
    const float resp1 = coord * ((b0 == 1 || b1 == 1) ? 1.0f : 0.0f);

    const float obj_conf = resp0 * dc0 * dc0 + resp1 * dc1 * dc1;

    float d;
    float center = 0.0f, wh = 0.0f;
    d = cp[0] - ct[0]; center += resp0 * d * d;
    d = cp[1] - ct[1]; center += resp0 * d * d;
    d = cp[5] - ct[5]; center += resp1 * d * d;
    d = cp[6] - ct[6]; center += resp1 * d * d;
    d = cp[2] - ct[2]; wh += resp0 * d * d;
    d = cp[3] - ct[3]; wh += resp0 * d * d;
    d = cp[7] - ct[7]; wh += resp1 * d * d;
    d = cp[8] - ct[8]; wh += resp1 * d * d;

    float cls = 0.0f;
    #pragma unroll
    for (int k = 10; k < 30; ++k) {
        d = cp[k] - ct[k];
        cls += d * d;
    }
    cls *= coord;

    float total = 5.0f * (center + wh) + obj_conf + 0.5f * noobj_conf + cls;

    // ---- reduction: wave shuffle -> LDS -> one atomic per block ----
    #pragma unroll
    for (int off = 32; off > 0; off >>= 1)
        total += __shfl_down(total, off, 64);

    const int wid = tid >> 6;
    const int lane = tid & 63;
    if (lane == 0) swave[wid] = total;
    __syncthreads();
    if (tid == 0) {
        float s = swave[0] + swave[1] + swave[2] + swave[3];
        atomicAdd(out, s);
    }
}

extern "C" void kernel_launch(void* const* d_in, const int* in_sizes, int n_in,
                              void* d_out, int out_size, void* d_ws, size_t ws_size,
                              hipStream_t stream) {
    const float* P = (const float*)d_in[0];
    const float* T = (const float*)d_in[1];
    float* out = (float*)d_out;

    hipMemsetAsync(out, 0, sizeof(float), stream);   // d_out is poisoned 0xAA
    yolo_loss_kernel<<<dim3(TOTAL_CELLS / CPB), dim3(TPB), 0, stream>>>(P, T, out);
}